// Round 4
// baseline (312.904 us; speedup 1.0000x reference)
//
#include <hip/hip_runtime.h>
#include <stdint.h>

#define BATCH 2048
#define SIZE 4096
#define DOWN 256
#define NTASK 16
#define KC 32
#define KCHUNK (SIZE / KC)   // 128
#define XPAD 128
#define ACTT_N (BATCH + XPAD)
#define BPITCH 130           // fp32 LDS row pitch: bank=(2k+n)%32 -> 2-way (free)

typedef _Float16 half8 __attribute__((ext_vector_type(8)));
typedef float floatx4 __attribute__((ext_vector_type(4)));

__device__ __forceinline__ int imin(int a, int b) { return a < b ? a : b; }

// async global->LDS. dest is wave-uniform; data lands at lds + lane*size.
// src is per-lane (pass base + lane).
__device__ __forceinline__ void async_cp16(void* lds, const void* g) {
    __builtin_amdgcn_global_load_lds((const __attribute__((address_space(1))) uint32_t*)g,
                                     (__attribute__((address_space(3))) uint32_t*)lds, 16, 0, 0);
}
__device__ __forceinline__ void async_cp4(void* lds, const void* g) {
    __builtin_amdgcn_global_load_lds((const __attribute__((address_space(1))) uint32_t*)g,
                                     (__attribute__((address_space(3))) uint32_t*)lds, 4, 0, 0);
}

// ---------------- counting sort: group samples by task ----------------
__global__ __launch_bounds__(256) void sort_kernel(const int* __restrict__ task_id,
                                                   int* __restrict__ taskOff,
                                                   int* __restrict__ sortedIdx,
                                                   int* __restrict__ taskOfPos) {
    __shared__ int cnt[NTASK];
    __shared__ int base[NTASK + 1];
    __shared__ int cur[NTASK];
    int tid = threadIdx.x;
    if (tid < NTASK) cnt[tid] = 0;
    __syncthreads();
    for (int i = tid; i < BATCH; i += 256) atomicAdd(&cnt[task_id[i]], 1);
    __syncthreads();
    if (tid == 0) {
        int s = 0;
        for (int t = 0; t < NTASK; t++) { base[t] = s; s += cnt[t]; }
        base[NTASK] = s;
    }
    __syncthreads();
    if (tid < NTASK) { cur[tid] = base[tid]; taskOff[tid] = base[tid]; }
    if (tid == 0) taskOff[NTASK] = BATCH;
    __syncthreads();
    for (int i = tid; i < BATCH; i += 256) {
        int t = task_id[i];
        int p = atomicAdd(&cur[t], 1);
        sortedIdx[p] = i;
        taskOfPos[p] = t;
    }
}

// ---------------- GEMM1: partial[kc][pos][h] = x @ Wd (K-split) ----------------
// grid (NTASK, KC, 2); 256 thr (4 waves, 2m x 2n); tile M=128 x N=128, BK=32.
// A: fp32 x rows -> cvt in register -> LDS k-pack-8. B: fp32 Wd -> async LDS,
// cvt at fragment read.
__global__ __launch_bounds__(256) void gemm1_kernel(const float* __restrict__ x,
                                                    const float* __restrict__ Wd,
                                                    const int* __restrict__ taskOff,
                                                    const int* __restrict__ sortedIdx,
                                                    _Float16* __restrict__ partial) {
    int task = blockIdx.x, kc = blockIdx.y, nt = blockIdx.z;
    int rowStart = taskOff[task];
    int nrows = taskOff[task + 1] - rowStart;
    if (nrows <= 0) return;

    __shared__ float B_ldsf[32 * BPITCH];   // 16.6 KB
    __shared__ half8 A_lds[4][128];         // 8 KB

    int tid = threadIdx.x;
    int wave = tid >> 6, lane = tid & 63, quad = lane >> 4, l15 = lane & 15;
    int wm = wave >> 1, wn = wave & 1;
    int rowA = tid >> 1, j2 = tid & 1;
    const float* Wdt = Wd + (size_t)task * SIZE * DOWN;

    for (int r0 = 0; r0 < nrows; r0 += 128) {
        floatx4 acc[4][4];
#pragma unroll
        for (int mi = 0; mi < 4; mi++)
#pragma unroll
            for (int ni = 0; ni < 4; ni++) acc[mi][ni] = (floatx4){0.f, 0.f, 0.f, 0.f};

        int asrc = sortedIdx[rowStart + imin(r0 + rowA, nrows - 1)];
        const float* xrow = x + (size_t)asrc * SIZE;

#pragma unroll
        for (int ph = 0; ph < 4; ph++) {
            int kglob = kc * KCHUNK + ph * 32;
            __syncthreads();
            // ---- A: 16 contiguous floats/thread -> 2 half8 -> LDS
            {
                const float* s = xrow + kglob + j2 * 16;
                float4 f0 = *(const float4*)(s);
                float4 f1 = *(const float4*)(s + 4);
                float4 f2 = *(const float4*)(s + 8);
                float4 f3 = *(const float4*)(s + 12);
                half8 h0, h1;
                h0[0] = (_Float16)f0.x; h0[1] = (_Float16)f0.y;
                h0[2] = (_Float16)f0.z; h0[3] = (_Float16)f0.w;
                h0[4] = (_Float16)f1.x; h0[5] = (_Float16)f1.y;
                h0[6] = (_Float16)f1.z; h0[7] = (_Float16)f1.w;
                h1[0] = (_Float16)f2.x; h1[1] = (_Float16)f2.y;
                h1[2] = (_Float16)f2.z; h1[3] = (_Float16)f2.w;
                h1[4] = (_Float16)f3.x; h1[5] = (_Float16)f3.y;
                h1[6] = (_Float16)f3.z; h1[7] = (_Float16)f3.w;
                A_lds[j2 * 2 + 0][rowA] = h0;
                A_lds[j2 * 2 + 1][rowA] = h1;
            }
            // ---- B: async fp32, 8 k-rows per wave, 2x 256B chunks per row
#pragma unroll
            for (int rr = 0; rr < 8; rr++) {
                int r = wave * 8 + rr;
                const float* src = Wdt + (size_t)(kglob + r) * DOWN + nt * 128 + lane;
                async_cp4(&B_ldsf[r * BPITCH], src);
                async_cp4(&B_ldsf[r * BPITCH + 64], src + 64);
            }
            __syncthreads();
            // ---- compute (one MFMA K=32 slab)
            half8 a[4], b[4];
#pragma unroll
            for (int i = 0; i < 4; i++) a[i] = A_lds[quad][wm * 64 + i * 16 + l15];
#pragma unroll
            for (int i = 0; i < 4; i++) {
                int n = wn * 64 + i * 16 + l15;
                const float* bp = &B_ldsf[quad * 8 * BPITCH + n];
#pragma unroll
                for (int j = 0; j < 8; j++) b[i][j] = (_Float16)bp[j * BPITCH];
            }
#pragma unroll
            for (int mi = 0; mi < 4; mi++)
#pragma unroll
                for (int ni = 0; ni < 4; ni++)
                    acc[mi][ni] = __builtin_amdgcn_mfma_f32_16x16x32_f16(
                        a[mi], b[ni], acc[mi][ni], 0, 0, 0);
        }
        // ---- epilogue: partial[kc][rowStart+r][h] fp16
#pragma unroll
        for (int mi = 0; mi < 4; mi++) {
#pragma unroll
            for (int reg = 0; reg < 4; reg++) {
                int r = r0 + wm * 64 + mi * 16 + quad * 4 + reg;
                if (r < nrows) {
                    size_t off = ((size_t)kc * BATCH + (rowStart + r)) * DOWN + nt * 128;
#pragma unroll
                    for (int ni = 0; ni < 4; ni++)
                        partial[off + wn * 64 + ni * 16 + l15] = (_Float16)acc[mi][ni][reg];
                }
            }
        }
    }
}

// ---------------- SiLU: actT[hg][pos] = silu(sum_kc partial + bd) ----------------
__global__ __launch_bounds__(256) void silu_kernel(const half8* __restrict__ partial8,
                                                   const float* __restrict__ bd,
                                                   const int* __restrict__ taskOfPos,
                                                   half8* __restrict__ actT) {
    int idx = blockIdx.x * 256 + threadIdx.x;  // BATCH*32
    int s = idx >> 5, hg = idx & 31;
    const float* bdr = bd + taskOfPos[s] * DOWN + hg * 8;
    float v[8];
#pragma unroll
    for (int e = 0; e < 8; e++) v[e] = bdr[e];
#pragma unroll
    for (int kc = 0; kc < KC; kc++) {
        half8 p = partial8[((size_t)kc * BATCH + s) * 32 + hg];
#pragma unroll
        for (int e = 0; e < 8; e++) v[e] += (float)p[e];
    }
    half8 h;
#pragma unroll
    for (int e = 0; e < 8; e++) {
        float sv = v[e] / (1.0f + __expf(-v[e]));
        h[e] = (_Float16)sv;
    }
    actT[(size_t)hg * ACTT_N + s] = h;
}

// ---------------- GEMM2: out = x + actT @ Wu + bu ----------------
// grid (NTASK, 32); 256 thr; tile M=128 x N=128, K=256, BK=64.
// A: fp16 actT panels via async size16. B: fp32 Wu via async size4 + cvt at read.
__global__ __launch_bounds__(256) void gemm2_kernel(const half8* __restrict__ actT,
                                                    const float* __restrict__ Wu,
                                                    const float* __restrict__ bu,
                                                    const float* __restrict__ x,
                                                    const int* __restrict__ taskOff,
                                                    const int* __restrict__ sortedIdx,
                                                    float* __restrict__ out) {
    int task = blockIdx.x, nt = blockIdx.y;
    int rowStart = taskOff[task];
    int nrows = taskOff[task + 1] - rowStart;
    if (nrows <= 0) return;

    __shared__ float B_ldsf[64 * BPITCH];   // 33.3 KB
    __shared__ half8 A_lds[8][128];         // 16 KB

    int tid = threadIdx.x;
    int wave = tid >> 6, lane = tid & 63, quad = lane >> 4, l15 = lane & 15;
    int wm = wave >> 1, wn = wave & 1;
    int ncol0 = nt * 128;
    const float* Wut = Wu + (size_t)task * DOWN * SIZE;

    for (int r0 = 0; r0 < nrows; r0 += 128) {
        floatx4 acc[4][4];
#pragma unroll
        for (int mi = 0; mi < 4; mi++)
#pragma unroll
            for (int ni = 0; ni < 4; ni++) acc[mi][ni] = (floatx4){0.f, 0.f, 0.f, 0.f};

#pragma unroll
        for (int ph = 0; ph < 4; ph++) {
            int kb = ph * 64;
            __syncthreads();
            // ---- A: 2 kg panels per wave, async 16B
#pragma unroll
            for (int jj = 0; jj < 2; jj++) {
                int j = wave * 2 + jj;
                const half8* src = actT + (size_t)(ph * 8 + j) * ACTT_N + rowStart + r0 + lane;
                async_cp16(&A_lds[j][0], src);
                async_cp16(&A_lds[j][64], src + 64);
            }
            // ---- B: async fp32, 16 k-rows per wave
#pragma unroll
            for (int rr = 0; rr < 16; rr++) {
                int r = wave * 16 + rr;
                const float* src = Wut + (size_t)(kb + r) * SIZE + ncol0 + lane;
                async_cp4(&B_ldsf[r * BPITCH], src);
                async_cp4(&B_ldsf[r * BPITCH + 64], src + 64);
            }
            __syncthreads();
#pragma unroll
            for (int ks = 0; ks < 2; ks++) {
                half8 a[4], b[4];
#pragma unroll
                for (int i = 0; i < 4; i++)
                    a[i] = A_lds[ks * 4 + quad][wm * 64 + i * 16 + l15];
#pragma unroll
                for (int i = 0; i < 4; i++) {
                    int n = wn * 64 + i * 16 + l15;
                    const float* bp = &B_ldsf[(ks * 32 + quad * 8) * BPITCH + n];
#pragma unroll
                    for (int j = 0; j < 8; j++) b[i][j] = (_Float16)bp[j * BPITCH];
                }
#pragma unroll
                for (int mi = 0; mi < 4; mi++)
#pragma unroll
                    for (int ni = 0; ni < 4; ni++)
                        acc[mi][ni] = __builtin_amdgcn_mfma_f32_16x16x32_f16(
                            a[mi], b[ni], acc[mi][ni], 0, 0, 0);
            }
        }
        // ---- epilogue: scatter to original rows, add bias + fp32 residual
#pragma unroll
        for (int mi = 0; mi < 4; mi++) {
#pragma unroll
            for (int reg = 0; reg < 4; reg++) {
                int r = r0 + wm * 64 + mi * 16 + quad * 4 + reg;
                if (r < nrows) {
                    int b = sortedIdx[rowStart + r];
                    const float* xr = x + (size_t)b * SIZE;
                    float* outr = out + (size_t)b * SIZE;
#pragma unroll
                    for (int ni = 0; ni < 4; ni++) {
                        int n = ncol0 + wn * 64 + ni * 16 + l15;
                        outr[n] = acc[mi][ni][reg] + bu[task * SIZE + n] + xr[n];
                    }
                }
            }
        }
    }
}

extern "C" void kernel_launch(void* const* d_in, const int* in_sizes, int n_in,
                              void* d_out, int out_size, void* d_ws, size_t ws_size,
                              hipStream_t stream) {
    const float* x       = (const float*)d_in[0];
    const int*   task_id = (const int*)d_in[1];
    const float* Wd      = (const float*)d_in[2];
    const float* bd      = (const float*)d_in[3];
    const float* Wu      = (const float*)d_in[4];
    const float* bu      = (const float*)d_in[5];
    float* out = (float*)d_out;

    // partial (KC*BATCH*DOWN fp16 = 32 MB) lives in d_out: dead before gemm2,
    // which overwrites every byte of d_out.
    _Float16* partial = (_Float16*)d_out;

    char* ws = (char*)d_ws;
    half8* actT = (half8*)ws;                 ws += (size_t)32 * ACTT_N * 16;  // ~1.1 MB
    int* taskOff   = (int*)ws;
    int* sortedIdx = taskOff + 32;
    int* taskOfPos = sortedIdx + BATCH;

    sort_kernel<<<1, 256, 0, stream>>>(task_id, taskOff, sortedIdx, taskOfPos);
    gemm1_kernel<<<dim3(NTASK, KC, 2), 256, 0, stream>>>(x, Wd, taskOff, sortedIdx, partial);
    silu_kernel<<<(BATCH * 32) / 256, 256, 0, stream>>>((const half8*)partial, bd, taskOfPos, actT);
    gemm2_kernel<<<dim3(NTASK, 32), 256, 0, stream>>>(actT, Wu, bu, x, taskOff,
                                                      sortedIdx, out);
}

// Round 5
// 249.955 us; speedup vs baseline: 1.2518x; 1.2518x over previous
//
#include <hip/hip_runtime.h>
#include <stdint.h>

#define BATCH 2048
#define SIZE 4096
#define DOWN 256
#define NTASK 16
#define KC 32
#define KCHUNK (SIZE / KC)   // 128
#define XPAD 128
#define ACTT_N (BATCH + XPAD)
#define BP 258               // fp32 LDS pitch: bank=(2k+n)%32 -> 2-way (free)

typedef _Float16 half8 __attribute__((ext_vector_type(8)));
typedef float floatx4 __attribute__((ext_vector_type(4)));

__device__ __forceinline__ int imin(int a, int b) { return a < b ? a : b; }

// ---------------- counting sort: group samples by task ----------------
__global__ __launch_bounds__(256) void sort_kernel(const int* __restrict__ task_id,
                                                   int* __restrict__ taskOff,
                                                   int* __restrict__ sortedIdx,
                                                   int* __restrict__ taskOfPos) {
    __shared__ int cnt[NTASK];
    __shared__ int base[NTASK + 1];
    __shared__ int cur[NTASK];
    int tid = threadIdx.x;
    if (tid < NTASK) cnt[tid] = 0;
    __syncthreads();
    for (int i = tid; i < BATCH; i += 256) atomicAdd(&cnt[task_id[i]], 1);
    __syncthreads();
    if (tid == 0) {
        int s = 0;
        for (int t = 0; t < NTASK; t++) { base[t] = s; s += cnt[t]; }
        base[NTASK] = s;
    }
    __syncthreads();
    if (tid < NTASK) { cur[tid] = base[tid]; taskOff[tid] = base[tid]; }
    if (tid == 0) taskOff[NTASK] = BATCH;
    __syncthreads();
    for (int i = tid; i < BATCH; i += 256) {
        int t = task_id[i];
        int p = atomicAdd(&cur[t], 1);
        sortedIdx[p] = i;
        taskOfPos[p] = t;
    }
}

// ---------------- GEMM1: partial[kc][pos][h] = x @ Wd ----------------
// grid (NTASK, KC, 32mt); 256 thr, 4 waves 1m x 4n; tile M=64 x N=256, BK=32.
// A: fp32 x -> cvt -> fp16 k-pack-8 LDS. B: float4 -> VGPR -> fp32 LDS, cvt at read.
__global__ __launch_bounds__(256) void gemm1_kernel(const float* __restrict__ x,
                                                    const float* __restrict__ Wd,
                                                    const int* __restrict__ taskOff,
                                                    const int* __restrict__ sortedIdx,
                                                    _Float16* __restrict__ partial) {
    int task = blockIdx.x, kc = blockIdx.y, mt = blockIdx.z;
    int rowStart = taskOff[task];
    int nrows = taskOff[task + 1] - rowStart;
    if (mt * 64 >= nrows) return;

    __shared__ float Bf[32 * BP];    // 33 KB
    __shared__ half8 A_lds[4][64];   // 4 KB

    int tid = threadIdx.x;
    int wave = tid >> 6, lane = tid & 63, quad = lane >> 4, l15 = lane & 15;
    int sArow = tid >> 2, sAkg = tid & 3;
    int bcol = (tid & 63) * 4;

    int asrc = sortedIdx[rowStart + imin(mt * 64 + sArow, nrows - 1)];
    const float* xrow = x + (size_t)asrc * SIZE;
    const float* Wdt = Wd + (size_t)task * SIZE * DOWN;

    floatx4 acc[4][4];
#pragma unroll
    for (int mi = 0; mi < 4; mi++)
#pragma unroll
        for (int ni = 0; ni < 4; ni++) acc[mi][ni] = (floatx4){0.f, 0.f, 0.f, 0.f};

#pragma unroll
    for (int ph = 0; ph < 4; ph++) {
        int k0 = kc * KCHUNK + ph * 32;
        __syncthreads();
        // ---- A: 8 consecutive fp32 -> half8 -> k-pack-8 LDS
        {
            const float* s = xrow + k0 + sAkg * 8;
            float4 f0 = *(const float4*)(s);
            float4 f1 = *(const float4*)(s + 4);
            half8 h;
            h[0] = (_Float16)f0.x; h[1] = (_Float16)f0.y;
            h[2] = (_Float16)f0.z; h[3] = (_Float16)f0.w;
            h[4] = (_Float16)f1.x; h[5] = (_Float16)f1.y;
            h[6] = (_Float16)f1.z; h[7] = (_Float16)f1.w;
            A_lds[sAkg][sArow] = h;
        }
        // ---- B: 8 float4 in flight -> LDS (rows 32 x 256 cols fp32)
        {
            float4 bv[8];
#pragma unroll
            for (int j = 0; j < 8; j++)
                bv[j] = *(const float4*)(Wdt + (size_t)(k0 + j * 4 + wave) * DOWN + bcol);
#pragma unroll
            for (int j = 0; j < 8; j++)
                *(float4*)&Bf[(j * 4 + wave) * BP + bcol] = bv[j];
        }
        __syncthreads();
        // ---- compute: one K=32 MFMA slab
        half8 a[4], b[4];
#pragma unroll
        for (int mi = 0; mi < 4; mi++) a[mi] = A_lds[quad][mi * 16 + l15];
#pragma unroll
        for (int ni = 0; ni < 4; ni++) {
            const float* bp = &Bf[quad * 8 * BP + wave * 64 + ni * 16 + l15];
#pragma unroll
            for (int j = 0; j < 8; j++) b[ni][j] = (_Float16)bp[j * BP];
        }
#pragma unroll
        for (int mi = 0; mi < 4; mi++)
#pragma unroll
            for (int ni = 0; ni < 4; ni++)
                acc[mi][ni] = __builtin_amdgcn_mfma_f32_16x16x32_f16(
                    a[mi], b[ni], acc[mi][ni], 0, 0, 0);
    }
    // ---- epilogue
#pragma unroll
    for (int mi = 0; mi < 4; mi++) {
#pragma unroll
        for (int reg = 0; reg < 4; reg++) {
            int r = mt * 64 + mi * 16 + quad * 4 + reg;
            if (r < nrows) {
                size_t off = ((size_t)kc * BATCH + (rowStart + r)) * DOWN;
#pragma unroll
                for (int ni = 0; ni < 4; ni++)
                    partial[off + wave * 64 + ni * 16 + l15] = (_Float16)acc[mi][ni][reg];
            }
        }
    }
}

// ---------------- SiLU: actT[hg][pos] = silu(sum_kc partial + bd) ----------------
__global__ __launch_bounds__(256) void silu_kernel(const half8* __restrict__ partial8,
                                                   const float* __restrict__ bd,
                                                   const int* __restrict__ taskOfPos,
                                                   half8* __restrict__ actT) {
    int idx = blockIdx.x * 256 + threadIdx.x;  // BATCH*32
    int s = idx >> 5, hg = idx & 31;
    const float* bdr = bd + taskOfPos[s] * DOWN + hg * 8;
    float v[8];
#pragma unroll
    for (int e = 0; e < 8; e++) v[e] = bdr[e];
#pragma unroll
    for (int kc = 0; kc < KC; kc++) {
        half8 p = partial8[((size_t)kc * BATCH + s) * 32 + hg];
#pragma unroll
        for (int e = 0; e < 8; e++) v[e] += (float)p[e];
    }
    half8 h;
#pragma unroll
    for (int e = 0; e < 8; e++) {
        float sv = v[e] / (1.0f + __expf(-v[e]));
        h[e] = (_Float16)sv;
    }
    actT[(size_t)hg * ACTT_N + s] = h;
}

// ---------------- GEMM2: out = x + actT @ Wu + bu ----------------
// grid (NTASK, 32nt, 32mt); 256 thr, 4 waves 1m x 4n; tile M=64 x N=128, K=256, BK=32.
__global__ __launch_bounds__(256) void gemm2_kernel(const half8* __restrict__ actT,
                                                    const float* __restrict__ Wu,
                                                    const float* __restrict__ bu,
                                                    const float* __restrict__ x,
                                                    const int* __restrict__ taskOff,
                                                    const int* __restrict__ sortedIdx,
                                                    float* __restrict__ out) {
    int task = blockIdx.x, nt = blockIdx.y, mt = blockIdx.z;
    int rowStart = taskOff[task];
    int nrows = taskOff[task + 1] - rowStart;
    if (mt * 64 >= nrows) return;

    __shared__ float Bf[32 * BP];    // 33 KB
    __shared__ half8 A_lds[4][64];   // 4 KB

    int tid = threadIdx.x;
    int wave = tid >> 6, lane = tid & 63, quad = lane >> 4, l15 = lane & 15;
    int sAhg = tid >> 6, sApos = tid & 63;
    int brow = tid >> 5, bcol = (tid & 31) * 4;
    int ncol0 = nt * 128;
    const float* Wut = Wu + (size_t)task * DOWN * SIZE;

    floatx4 acc[4][2];
#pragma unroll
    for (int mi = 0; mi < 4; mi++)
#pragma unroll
        for (int ni = 0; ni < 2; ni++) acc[mi][ni] = (floatx4){0.f, 0.f, 0.f, 0.f};

#pragma unroll
    for (int ph = 0; ph < 8; ph++) {
        int kb = ph * 32;
        __syncthreads();
        // ---- A: fp16 k-pack-8 panel, 1x16B per thread
        A_lds[sAhg][sApos] =
            actT[(size_t)(ph * 4 + sAhg) * ACTT_N + rowStart + mt * 64 + sApos];
        // ---- B: 4 float4 in flight -> LDS (32 k-rows x 128 cols fp32)
        {
            float4 bv[4];
#pragma unroll
            for (int j = 0; j < 4; j++)
                bv[j] = *(const float4*)(Wut + (size_t)(kb + j * 8 + brow) * SIZE + ncol0 + bcol);
#pragma unroll
            for (int j = 0; j < 4; j++)
                *(float4*)&Bf[(j * 8 + brow) * BP + bcol] = bv[j];
        }
        __syncthreads();
        half8 a[4], b[2];
#pragma unroll
        for (int mi = 0; mi < 4; mi++) a[mi] = A_lds[quad][mi * 16 + l15];
#pragma unroll
        for (int ni = 0; ni < 2; ni++) {
            const float* bp = &Bf[quad * 8 * BP + wave * 32 + ni * 16 + l15];
#pragma unroll
            for (int j = 0; j < 8; j++) b[ni][j] = (_Float16)bp[j * BP];
        }
#pragma unroll
        for (int mi = 0; mi < 4; mi++)
#pragma unroll
            for (int ni = 0; ni < 2; ni++)
                acc[mi][ni] = __builtin_amdgcn_mfma_f32_16x16x32_f16(
                    a[mi], b[ni], acc[mi][ni], 0, 0, 0);
    }
    // ---- epilogue: scatter + bias + residual
#pragma unroll
    for (int mi = 0; mi < 4; mi++) {
#pragma unroll
        for (int reg = 0; reg < 4; reg++) {
            int r = mt * 64 + mi * 16 + quad * 4 + reg;
            if (r < nrows) {
                int bidx = sortedIdx[rowStart + r];
                const float* xr = x + (size_t)bidx * SIZE;
                float* outr = out + (size_t)bidx * SIZE;
#pragma unroll
                for (int ni = 0; ni < 2; ni++) {
                    int n = ncol0 + wave * 32 + ni * 16 + l15;
                    outr[n] = acc[mi][ni][reg] + bu[task * SIZE + n] + xr[n];
                }
            }
        }
    }
}

extern "C" void kernel_launch(void* const* d_in, const int* in_sizes, int n_in,
                              void* d_out, int out_size, void* d_ws, size_t ws_size,
                              hipStream_t stream) {
    const float* x       = (const float*)d_in[0];
    const int*   task_id = (const int*)d_in[1];
    const float* Wd      = (const float*)d_in[2];
    const float* bd      = (const float*)d_in[3];
    const float* Wu      = (const float*)d_in[4];
    const float* bu      = (const float*)d_in[5];
    float* out = (float*)d_out;

    // partial (KC*BATCH*DOWN fp16 = 32 MB) lives in d_out: dead before gemm2,
    // which overwrites every byte of d_out.
    _Float16* partial = (_Float16*)d_out;

    char* ws = (char*)d_ws;
    half8* actT = (half8*)ws;                 ws += (size_t)32 * ACTT_N * 16;  // ~1.1 MB
    int* taskOff   = (int*)ws;
    int* sortedIdx = taskOff + 32;
    int* taskOfPos = sortedIdx + BATCH;

    sort_kernel<<<1, 256, 0, stream>>>(task_id, taskOff, sortedIdx, taskOfPos);
    gemm1_kernel<<<dim3(NTASK, KC, 32), 256, 0, stream>>>(x, Wd, taskOff, sortedIdx, partial);
    silu_kernel<<<(BATCH * 32) / 256, 256, 0, stream>>>((const half8*)partial, bd, taskOfPos, actT);
    gemm2_kernel<<<dim3(NTASK, 32, 32), 256, 0, stream>>>(actT, Wu, bu, x, taskOff,
                                                          sortedIdx, out);
}